// Round 2
// baseline (49.351 us; speedup 1.0000x reference)
//
#include <hip/hip_runtime.h>
#include <math.h>

// Problem: x is (64, 1048576) f32 = 64M elements. Reference returns True
// iff argmax-with-lowest-index-ties != argmax-with-highest-index-ties, i.e.
// iff the global maximum value occurs at more than one index.
// Output dtype is bool -> harness reads d_out as int32 (round-1 lesson:
// absmax error was exactly bits(1.0f)-1). Store int 0/1, not float.
// Kernel: streaming tie-aware argmax reduction. Memory-bound (256 MiB read).

#define NB 2048   // blocks (cap per G11; d_ws usage = NB*12 B = 24 KiB)
#define NT 256    // threads per block (4 waves)

struct Trip { float v; int imin; int imax; };

__device__ __forceinline__ void upd(float x, int idx, float& v, int& imin, int& imax) {
    if (x > v)      { v = x; imin = idx; imax = idx; }
    else if (x == v){ if (idx < imin) imin = idx; if (idx > imax) imax = idx; }
}

__device__ __forceinline__ void merge(float bv, int bmn, int bmx,
                                      float& v, int& imin, int& imax) {
    if (bv > v)       { v = bv; imin = bmn; imax = bmx; }
    else if (bv == v) { if (bmn < imin) imin = bmn; if (bmx > imax) imax = bmx; }
}

__global__ __launch_bounds__(NT) void argmax_part(const float4* __restrict__ x,
                                                  Trip* __restrict__ part, int n4) {
    const int tid = blockIdx.x * NT + threadIdx.x;
    const int stride = NB * NT;
    float v = -INFINITY; int imin = 0x7fffffff, imax = -1;
    for (int i = tid; i < n4; i += stride) {
        float4 f = x[i];
        int b = i << 2;
        upd(f.x, b,     v, imin, imax);
        upd(f.y, b + 1, v, imin, imax);
        upd(f.z, b + 2, v, imin, imax);
        upd(f.w, b + 3, v, imin, imax);
    }

    __shared__ float sv[NT];
    __shared__ int   smn[NT], smx[NT];
    const int t = threadIdx.x;
    sv[t] = v; smn[t] = imin; smx[t] = imax;
    __syncthreads();
    for (int s = NT / 2; s > 0; s >>= 1) {
        if (t < s) {
            float av = sv[t]; int amn = smn[t], amx = smx[t];
            merge(sv[t + s], smn[t + s], smx[t + s], av, amn, amx);
            sv[t] = av; smn[t] = amn; smx[t] = amx;
        }
        __syncthreads();
    }
    if (t == 0) { part[blockIdx.x].v = sv[0]; part[blockIdx.x].imin = smn[0]; part[blockIdx.x].imax = smx[0]; }
}

__global__ __launch_bounds__(NT) void argmax_final(const Trip* __restrict__ part,
                                                   const float* __restrict__ x,
                                                   int n4, int n,
                                                   int* __restrict__ out) {
    const int t = threadIdx.x;
    float v = -INFINITY; int imin = 0x7fffffff, imax = -1;
    for (int i = t; i < NB; i += NT) {
        Trip p = part[i];
        merge(p.v, p.imin, p.imax, v, imin, imax);
    }
    // Tail elements (n not divisible by 4) — none for this shape, but be safe.
    for (int i = n4 * 4 + t; i < n; i += NT) upd(x[i], i, v, imin, imax);

    __shared__ float sv[NT];
    __shared__ int   smn[NT], smx[NT];
    sv[t] = v; smn[t] = imin; smx[t] = imax;
    __syncthreads();
    for (int s = NT / 2; s > 0; s >>= 1) {
        if (t < s) {
            float av = sv[t]; int amn = smn[t], amx = smx[t];
            merge(sv[t + s], smn[t + s], smx[t + s], av, amn, amx);
            sv[t] = av; smn[t] = amn; smx[t] = amx;
        }
        __syncthreads();
    }
    if (t == 0) out[0] = (smn[0] != smx[0]) ? 1 : 0;
}

extern "C" void kernel_launch(void* const* d_in, const int* in_sizes, int n_in,
                              void* d_out, int out_size, void* d_ws, size_t ws_size,
                              hipStream_t stream) {
    const float* x = (const float*)d_in[0];
    const int n  = in_sizes[0];      // 67108864
    const int n4 = n >> 2;
    Trip* part = (Trip*)d_ws;        // 2048 * 12 B = 24 KiB scratch

    argmax_part <<<NB, NT, 0, stream>>>((const float4*)x, part, n4);
    argmax_final<<<1,  NT, 0, stream>>>(part, x, n4, n, (int*)d_out);
}